// Round 3
// baseline (619.709 us; speedup 1.0000x reference)
//
#include <hip/hip_runtime.h>
#include <hip/hip_bf16.h>
#include <stdint.h>

typedef __hip_bfloat16 bf16;
typedef __attribute__((ext_vector_type(8))) short bf16x8;    // 8 bf16 = 4 VGPRs
typedef __attribute__((ext_vector_type(16))) float f32x16;   // 32x32 accumulator

static constexpr int Mtot = 8192;   // B*T
static constexpr int Ktot = 4096;   // DIN
static constexpr int Ntot = 4096;   // DOUT
static constexpr int BM = 128, BN = 128, BK = 32;
static constexpr int NK = Ktot / BK;            // 128
static constexpr int CAST_BLOCKS = (Mtot * Ktot / 8) / 256;  // 16384
static constexpr int PREP_BLOCKS = (Ntot * Ktot / 8) / 256;  // 2048

__device__ __forceinline__ void gl_lds16(const void* g, void* l) {
  __builtin_amdgcn_global_load_lds(
      (const __attribute__((address_space(1))) void*)g,
      (__attribute__((address_space(3))) void*)l,
      16, 0, 0);
}

__device__ __forceinline__ uint32_t bf16pair(float a, float b) {
  __hip_bfloat16 ha = __float2bfloat16(a), hb = __float2bfloat16(b);
  uint16_t ia, ib;
  __builtin_memcpy(&ia, &ha, 2);
  __builtin_memcpy(&ib, &hb, 2);
  return (uint32_t)ia | ((uint32_t)ib << 16);
}

// ---------- fused prep: cast x -> bf16  AND  W_eff -> bf16 ----------
__global__ __launch_bounds__(256) void prep_kernel(const float* __restrict__ x,
                                                   bf16* __restrict__ xb,
                                                   const float* __restrict__ W,
                                                   const float* __restrict__ U,
                                                   const float* __restrict__ S,
                                                   const float* __restrict__ Vh,
                                                   const float* __restrict__ P,
                                                   const float* __restrict__ v,
                                                   bf16* __restrict__ Wp) {
  const int bid = blockIdx.x;
  if (bid < CAST_BLOCKS) {
    size_t gid = (size_t)bid * 256 + threadIdx.x;
    size_t d0 = gid * 8;
    const float4 a = ((const float4*)(x + d0))[0];
    const float4 b = ((const float4*)(x + d0))[1];
    uint4 pk;
    pk.x = bf16pair(a.x, a.y);
    pk.y = bf16pair(a.z, a.w);
    pk.z = bf16pair(b.x, b.y);
    pk.w = bf16pair(b.z, b.w);
    ((uint4*)(xb + d0))[0] = pk;
  } else {
    float R0 = 0.f, R1 = 0.f, R2 = 0.f, R3 = 0.f;
#pragma unroll
    for (int u = 0; u < 16; ++u) {
      float vu = v[u];
      R0 += vu * P[u * 4 + 0];
      R1 += vu * P[u * 4 + 1];
      R2 += vu * P[u * 4 + 2];
      R3 += vu * P[u * 4 + 3];
    }
    float SR00 = S[0] * R0 + S[1] * R2, SR01 = S[0] * R1 + S[1] * R3;
    float SR10 = S[2] * R0 + S[3] * R2, SR11 = S[2] * R1 + S[3] * R3;

    int gid = (bid - CAST_BLOCKS) * 256 + threadIdx.x;
    int o = gid >> 9;
    int d0 = (gid & 511) << 3;
    float u0 = U[o * 2 + 0], u1 = U[o * 2 + 1];
    float M0 = u0 * SR00 + u1 * SR10;
    float M1 = u0 * SR01 + u1 * SR11;

    const float* wrow = W + (size_t)o * Ktot + d0;
    const float4 w0 = ((const float4*)wrow)[0];
    const float4 w1 = ((const float4*)wrow)[1];
    const float4 a0 = ((const float4*)(Vh + d0))[0];
    const float4 a1 = ((const float4*)(Vh + d0))[1];
    const float4 b0 = ((const float4*)(Vh + Ktot + d0))[0];
    const float4 b1 = ((const float4*)(Vh + Ktot + d0))[1];
    float val[8];
    val[0] = w0.x + M0 * a0.x + M1 * b0.x;
    val[1] = w0.y + M0 * a0.y + M1 * b0.y;
    val[2] = w0.z + M0 * a0.z + M1 * b0.z;
    val[3] = w0.w + M0 * a0.w + M1 * b0.w;
    val[4] = w1.x + M0 * a1.x + M1 * b1.x;
    val[5] = w1.y + M0 * a1.y + M1 * b1.y;
    val[6] = w1.z + M0 * a1.z + M1 * b1.z;
    val[7] = w1.w + M0 * a1.w + M1 * b1.w;
    uint4 pk;
    pk.x = bf16pair(val[0], val[1]);
    pk.y = bf16pair(val[2], val[3]);
    pk.z = bf16pair(val[4], val[5]);
    pk.w = bf16pair(val[6], val[7]);
    ((uint4*)(Wp + (size_t)o * Ktot + d0))[0] = pk;
  }
}

// ---------- main GEMM: out = A @ Bt^T + bias ----------
// 32x32x16 MFMA (half the issue slots of 16x16x32 for the same FLOPs).
// LDS double-buffered; XOR chunk swizzle c' = c ^ (row & 3) keeps both the
// global_load_lds contiguity constraint AND conflict-free ds_read_b128
// (reads walk 32 consecutive rows -> need period-4 row swizzle).
__global__ __launch_bounds__(256) void gemm_kernel(const bf16* __restrict__ A,
                                                   const bf16* __restrict__ Bt,
                                                   const float* __restrict__ bias,
                                                   float* __restrict__ out) {
  __shared__ __align__(16) bf16 As[2][BM * BK];
  __shared__ __align__(16) bf16 Bs[2][BN * BK];

  const int tid = threadIdx.x;
  const int lane = tid & 63;
  const int wv = tid >> 6;                // 0..3
  const int m0 = blockIdx.y * BM;
  const int n0 = blockIdx.x * BN;

  // ---- staging: each wave covers 32 rows of A and 32 rows of B ----
  const int lrow = lane >> 2;                        // 0..15
  const int lk = (((lane & 3) ^ (lrow & 3)) << 3);   // swizzled chunk, elems

  const bf16* ga0 = A + (size_t)(m0 + wv * 32 + lrow) * Ktot + lk;
  const bf16* ga1 = ga0 + (size_t)16 * Ktot;
  const bf16* gb0 = Bt + (size_t)(n0 + wv * 32 + lrow) * Ktot + lk;
  const bf16* gb1 = gb0 + (size_t)16 * Ktot;
  const int laoff0 = (wv * 32) * BK;
  const int laoff1 = (wv * 32 + 16) * BK;

  // ---- compute: wave -> 64x64 subtile (2x2 of 32x32, 2 k-steps of 16) ----
  const int moff = (wv >> 1) * 64;
  const int noff = (wv & 1) * 64;
  const int rm = lane & 31;               // row within 32-tile
  const int half = lane >> 5;             // k-half select
  const int rs = rm & 3;                  // row swizzle key

  f32x16 acc[2][2];
#pragma unroll
  for (int i = 0; i < 2; ++i)
#pragma unroll
    for (int j = 0; j < 2; ++j)
#pragma unroll
      for (int r = 0; r < 16; ++r) acc[i][j][r] = 0.f;

  // prologue: stage tile 0 into buffer 0
  gl_lds16(ga0, &As[0][laoff0]);
  gl_lds16(ga1, &As[0][laoff1]);
  gl_lds16(gb0, &Bs[0][laoff0]);
  gl_lds16(gb1, &Bs[0][laoff1]);
  ga0 += BK; ga1 += BK; gb0 += BK; gb1 += BK;
  __syncthreads();   // vmcnt(0) drain: tile 0 resident

  for (int kt = 0; kt < NK; ++kt) {
    const int cur = kt & 1;
    if (kt + 1 < NK) {
      const int nxt = cur ^ 1;
      gl_lds16(ga0, &As[nxt][laoff0]);
      gl_lds16(ga1, &As[nxt][laoff1]);
      gl_lds16(gb0, &Bs[nxt][laoff0]);
      gl_lds16(gb1, &Bs[nxt][laoff1]);
      ga0 += BK; ga1 += BK; gb0 += BK; gb1 += BK;
    }

    const bf16* pa = &As[cur][0];
    const bf16* pb = &Bs[cur][0];
    bf16x8 av[2][2], bv[2][2];   // [tile][ksub]
#pragma unroll
    for (int i = 0; i < 2; ++i)
#pragma unroll
      for (int ks = 0; ks < 2; ++ks)
        av[i][ks] = *(const bf16x8*)(pa + (moff + i * 32 + rm) * BK +
                                     (((ks * 2 + half) ^ rs) << 3));
#pragma unroll
    for (int j = 0; j < 2; ++j)
#pragma unroll
      for (int ks = 0; ks < 2; ++ks)
        bv[j][ks] = *(const bf16x8*)(pb + (noff + j * 32 + rm) * BK +
                                     (((ks * 2 + half) ^ rs) << 3));
#pragma unroll
    for (int ks = 0; ks < 2; ++ks)
#pragma unroll
      for (int i = 0; i < 2; ++i)
#pragma unroll
        for (int j = 0; j < 2; ++j)
          acc[i][j] = __builtin_amdgcn_mfma_f32_32x32x16_bf16(av[i][ks], bv[j][ks],
                                                              acc[i][j], 0, 0, 0);

    __syncthreads();   // readers done with cur; next-tile loads drained
  }

  // epilogue: C/D layout col = lane&31, row = (reg&3) + 8*(reg>>2) + 4*(lane>>5)
#pragma unroll
  for (int j = 0; j < 2; ++j) {
    const int gn = n0 + noff + j * 32 + rm;
    const float bj = bias[gn];
#pragma unroll
    for (int i = 0; i < 2; ++i) {
      const int gmb = m0 + moff + i * 32 + 4 * half;
#pragma unroll
      for (int r = 0; r < 16; ++r) {
        const int grow = gmb + (r & 3) + 8 * (r >> 2);
        out[(size_t)grow * Ntot + gn] = acc[i][j][r] + bj;
      }
    }
  }
}

extern "C" void kernel_launch(void* const* d_in, const int* in_sizes, int n_in,
                              void* d_out, int out_size, void* d_ws, size_t ws_size,
                              hipStream_t stream) {
  const float* x  = (const float*)d_in[0];
  const float* W  = (const float*)d_in[1];
  const float* b  = (const float*)d_in[2];
  const float* U  = (const float*)d_in[3];
  const float* S  = (const float*)d_in[4];
  const float* Vh = (const float*)d_in[5];
  const float* P  = (const float*)d_in[6];
  const float* v  = (const float*)d_in[7];
  float* out = (float*)d_out;

  bf16* xb = (bf16*)d_ws;                                    // 67,108,864 B
  bf16* Wp = (bf16*)((char*)d_ws + (size_t)Mtot * Ktot * 2); // +33,554,432 B

  prep_kernel<<<CAST_BLOCKS + PREP_BLOCKS, 256, 0, stream>>>(x, xb, W, U, S, Vh, P, v, Wp);

  dim3 grid(Ntot / BN, Mtot / BM);  // (32, 64)
  gemm_kernel<<<grid, 256, 0, stream>>>(xb, Wp, b, out);
}